// Round 15
// baseline (43.349 us; speedup 1.0000x reference)
//
#include <hip/hip_runtime.h>
#include <hip/hip_bf16.h>

typedef __attribute__((ext_vector_type(4))) float f32x4;
typedef __attribute__((ext_vector_type(2))) long i64x2;

typedef const __attribute__((address_space(1))) void* gptr_t;
typedef __attribute__((address_space(3))) void* lptr_t;

#define NROW 8192
#define DDIM 256
#define HALF_B 4096
#define NB 64                        // 8192/128 tile bands
#define NTILES (NB * (NB + 1) / 2)   // 2080 upper-triangle tiles
#define NPAIRS (NTILES / 2)          // 1040 blocks, 2 tiles each

// exp(dot/T) = exp2(dot * log2(e)/T), T = 0.07
#define E2SCALE 20.6099291555566196f
#define INV_T   14.2857142857142858f

__device__ __forceinline__ float fast_exp2(float x) {
  float r;
  asm("v_exp_f32 %0, %1" : "=v"(r) : "v"(x));
  return r;
}

// ---------------- kernel 1: normalize + fp8(e4m3) quant, paired layout -----
// (unchanged from R14 — passed, absmax 0)
__global__ __launch_bounds__(256) void normalize_kernel(
    const float* __restrict__ z_i, const float* __restrict__ z_j,
    unsigned char* __restrict__ zn, float* __restrict__ lacc,
    unsigned int* __restrict__ counter) {
  const int lane = threadIdx.x & 63;
  const int w = blockIdx.x * 4 + (threadIdx.x >> 6);  // wave id 0..2047
  const int g  = (lane >> 1) & 3;
  const int e  = (lane >> 3) & 1;
  const int ph = (lane >> 4) & 1;     // p&1
  const int pq = lane >> 5;           // p>>1
  const int o  = (lane & 1) * 4;
  const int cbase = (ph << 2) | g;
  for (int row = w; row < NROW; row += 2048) {
    const float* src = (row < HALF_B) ? (z_i + (size_t)row * DDIM)
                                      : (z_j + (size_t)(row - HALF_B) * DDIM);
    float4 v = *reinterpret_cast<const float4*>(src + lane * 4);
    float ss = v.x * v.x + v.y * v.y + v.z * v.z + v.w * v.w;
#pragma unroll
    for (int m = 32; m; m >>= 1) ss += __shfl_xor(ss, m);
    const float inv = 1.0f / sqrtf(ss);
    int pk = __builtin_amdgcn_cvt_pk_fp8_f32(v.x * inv, v.y * inv, 0, false);
    pk = __builtin_amdgcn_cvt_pk_fp8_f32(v.z * inv, v.w * inv, pk, true);
    const int pos = pq * 128 + ((cbase ^ (row & 7)) << 4) + e * 8 + o;
    *reinterpret_cast<unsigned int*>(zn + (size_t)row * DDIM + pos) =
        (unsigned int)pk;
  }
  if (blockIdx.x == 0 && threadIdx.x == 0) { *lacc = 0.0f; *counter = 0u; }
}

// ---------------- kernel 2: paired upper-triangle 128x128 Gram tiles --------
// 1040 blocks x 2 consecutive tiles. 512 thr = 8 waves (2x4), wave 64x32.
// A (32KB @0) persists across the pair when both tiles share a band (94%):
// staged once. B (32KB @32768) staged per tile; rowmat (32KB, XOR-swizzled)
// ALIASES the B region during the epilogue. colxch (1KB @65536) for the
// cross-wave (wr0+wr1) column-sum exchange. T4 counted-vmcnt per tile.
__global__ __launch_bounds__(512, 4) void gram_kernel(
    const unsigned char* __restrict__ zn,
    float* __restrict__ P, float* __restrict__ pos) {
  __shared__ char smem[66560];   // A0@0 A1@16K | B0@32K B1@48K | colxch@64K

  const int tid = threadIdx.x;
  const int lane = tid & 63;
  const int wid = tid >> 6;          // 0..7
  const int wr = wid >> 2;           // 0..1 (64 rows each)
  const int wc = wid & 3;            // 0..3 (32 cols each)
  const int rloc = tid >> 3;
  const int c16 = (tid & 7) * 16;
  const int r15 = lane & 15, g = lane >> 4, r7 = lane & 7;
  const int abase = (wr * 64 + r15) * 128;
  const int bbase = (wc * 32 + r15) * 128;
  float* colxch = (float*)(smem + 65536);

  // stage one tile's A and/or B (half-K h=0 loads issued first)
  auto stageTile = [&](int rowB, int colB, bool withA) {
#pragma unroll
    for (int h = 0; h < 2; ++h) {
#pragma unroll
      for (int t = 0; t < 2; ++t) {
        const int r = t * 64 + rloc;
        if (withA) {
          const unsigned char* ga =
              zn + (size_t)(rowB + r) * DDIM + h * 128 + c16;
          __builtin_amdgcn_global_load_lds((gptr_t)ga,
              (lptr_t)(smem + h * 16384 + t * 8192 + wid * 1024), 16, 0, 0);
        }
        const unsigned char* gb =
            zn + (size_t)(colB + r) * DDIM + h * 128 + c16;
        __builtin_amdgcn_global_load_lds((gptr_t)gb,
            (lptr_t)(smem + 32768 + h * 16384 + t * 8192 + wid * 1024),
            16, 0, 0);
      }
    }
  };

  auto runTile = [&](int rowB, int colB, bool withA) {
    // h0 ready when only h1's loads remain outstanding
    if (withA) { asm volatile("s_waitcnt vmcnt(4)" ::: "memory"); }
    else       { asm volatile("s_waitcnt vmcnt(2)" ::: "memory"); }
    __builtin_amdgcn_s_barrier();
    __builtin_amdgcn_sched_barrier(0);

    f32x4 acc[4][2] = {};
#pragma unroll
    for (int h = 0; h < 2; ++h) {
      if (h == 1) {
        asm volatile("s_waitcnt vmcnt(0)" ::: "memory");
        __builtin_amdgcn_s_barrier();
        __builtin_amdgcn_sched_barrier(0);
      }
      const char* Ab = reinterpret_cast<const char*>(smem) + h * 16384;
      const char* Bb = reinterpret_cast<const char*>(smem) + 32768 + h * 16384;
#pragma unroll
      for (int lp = 0; lp < 2; ++lp) {
        const int off = ((((lp << 2) | g) ^ r7) << 4);
        i64x2 A0 = *reinterpret_cast<const i64x2*>(Ab + abase + off);
        i64x2 A1 = *reinterpret_cast<const i64x2*>(Ab + abase + 2048 + off);
        i64x2 A2 = *reinterpret_cast<const i64x2*>(Ab + abase + 4096 + off);
        i64x2 A3 = *reinterpret_cast<const i64x2*>(Ab + abase + 6144 + off);
        i64x2 B0 = *reinterpret_cast<const i64x2*>(Bb + bbase + off);
        i64x2 B1 = *reinterpret_cast<const i64x2*>(Bb + bbase + 2048 + off);
#pragma unroll
        for (int e = 0; e < 2; ++e) {
          const long a0 = A0[e], a1 = A1[e], a2 = A2[e], a3 = A3[e];
          const long b0 = B0[e], b1 = B1[e];
          acc[0][0] = __builtin_amdgcn_mfma_f32_16x16x32_fp8_fp8(a0, b0, acc[0][0], 0, 0, 0);
          acc[0][1] = __builtin_amdgcn_mfma_f32_16x16x32_fp8_fp8(a0, b1, acc[0][1], 0, 0, 0);
          acc[1][0] = __builtin_amdgcn_mfma_f32_16x16x32_fp8_fp8(a1, b0, acc[1][0], 0, 0, 0);
          acc[1][1] = __builtin_amdgcn_mfma_f32_16x16x32_fp8_fp8(a1, b1, acc[1][1], 0, 0, 0);
          acc[2][0] = __builtin_amdgcn_mfma_f32_16x16x32_fp8_fp8(a2, b0, acc[2][0], 0, 0, 0);
          acc[2][1] = __builtin_amdgcn_mfma_f32_16x16x32_fp8_fp8(a2, b1, acc[2][1], 0, 0, 0);
          acc[3][0] = __builtin_amdgcn_mfma_f32_16x16x32_fp8_fp8(a3, b0, acc[3][0], 0, 0, 0);
          acc[3][1] = __builtin_amdgcn_mfma_f32_16x16x32_fp8_fp8(a3, b1, acc[3][1], 0, 0, 0);
        }
      }
    }
    __syncthreads();   // all A/B reads done; B region becomes rowmat

    const bool isdiag = (rowB == colB);
    const bool ispos = (colB - rowB == HALF_B * 0 + 4096);

    // ---- epilogue ph1: exp, scatter row-parts into swizzled rowmat (B region)
    char* rowm = smem + 32768;
    const int col = wc * 16 + r15;               // 0..63
    float colpart[2] = {0.0f, 0.0f};
#pragma unroll
    for (int m = 0; m < 4; ++m) {
#pragma unroll
      for (int v = 0; v < 4; ++v) {
        const int lrow = wr * 64 + m * 16 + (lane >> 4) * 4 + v;
        const int gi = rowB + lrow;
        float rp = 0.0f;
#pragma unroll
        for (int n = 0; n < 2; ++n) {
          const float d = acc[m][n][v];
          float val = fast_exp2(d * E2SCALE);
          if (isdiag) {
            const int gj = colB + wc * 32 + n * 16 + r15;
            if (gi == gj) val = 0.0f;           // exclude diagonal
          } else if (ispos) {
            const int gj = colB + wc * 32 + n * 16 + r15;
            if (gj == gi + 4096) {              // positive pair
              const float pv = d * INV_T;
              pos[gi] = pv;
              pos[gj] = pv;
            }
          }
          rp += val;
          colpart[n] += val;
        }
        const int bo = (lrow << 8) + ((((col >> 2) ^ (lrow & 15)) << 4)) +
                       ((col & 3) << 2);
        *reinterpret_cast<float*>(rowm + bo) = rp;
      }
    }
    // column partial: reduce over this wave's 4 row-groups (64 rows of wr)
    float cred[2];
#pragma unroll
    for (int n = 0; n < 2; ++n) {
      float c = colpart[n];
      c += __shfl_xor(c, 16);
      c += __shfl_xor(c, 32);
      cred[n] = c;
    }
    if (wr == 0 && lane < 16) {
      colxch[wc * 32 + lane] = cred[0];
      colxch[wc * 32 + 16 + lane] = cred[1];
    }
    __syncthreads();

    // ---- epilogue ph2: rowmat read-reduce -> P rows; wr1 adds colxch -> P cols
    {
      const int row = tid >> 2;          // 0..127
      const int seg = tid & 3;           // 4 threads/row, 16 floats each
      const char* base = rowm + (row << 8);
      f32x4 s4 = {0.0f, 0.0f, 0.0f, 0.0f};
#pragma unroll
      for (int i = 0; i < 4; ++i) {
        s4 += *reinterpret_cast<const f32x4*>(
            base + ((((seg << 2) | i) ^ (row & 15)) << 4));
      }
      float s = (s4[0] + s4[1]) + (s4[2] + s4[3]);
      s += __shfl_xor(s, 1);
      s += __shfl_xor(s, 2);
      if (seg == 0) P[(size_t)(colB >> 7) * NROW + rowB + row] = s;
    }
    if (!isdiag && wr == 1 && lane < 16) {
      const int cl0 = wc * 32 + lane, cl1 = cl0 + 16;
      P[(size_t)(rowB >> 7) * NROW + colB + cl0] = cred[0] + colxch[cl0];
      P[(size_t)(rowB >> 7) * NROW + colB + cl1] = cred[1] + colxch[cl1];
    }
    __syncthreads();   // protect rowmat/colxch before next tile's staging
  };

  // ---- decode pair: tiles 2*bid, 2*bid+1 (consecutive in tri-order)
  int p = blockIdx.x * 2;
  int by0 = 0;
  while (p >= NB - by0) { p -= NB - by0; ++by0; }
  const int bx0 = by0 + p;
  int by1, bx1;
  if (bx0 < NB - 1) { by1 = by0; bx1 = bx0 + 1; }
  else              { by1 = by0 + 1; bx1 = by1; }
  const bool sameA = (by1 == by0);

  stageTile(by0 * 128, bx0 * 128, true);
  runTile(by0 * 128, bx0 * 128, true);
  stageTile(by1 * 128, bx1 * 128, !sameA);
  runTile(by1 * 128, bx1 * 128, !sameA);
}

// -------- kernel 3: row reduction + log + fused finalize (arrival counter) --
__global__ __launch_bounds__(256) void rowreduce_kernel(
    const float* __restrict__ P, const float* __restrict__ pos,
    float* __restrict__ lacc, unsigned int* __restrict__ counter,
    float* __restrict__ out) {
  const int i = blockIdx.x * 256 + threadIdx.x;
  float s = 0.0f;
#pragma unroll 8
  for (int k = 0; k < NB; ++k) s += P[(size_t)k * NROW + i];
  float partial = logf(s) - pos[i];
#pragma unroll
  for (int m = 32; m; m >>= 1) partial += __shfl_xor(partial, m);
  __shared__ float sred[4];
  if ((threadIdx.x & 63) == 0) sred[threadIdx.x >> 6] = partial;
  __syncthreads();
  if (threadIdx.x == 0) {
    atomicAdd(lacc, sred[0] + sred[1] + sred[2] + sred[3]);
    __threadfence();
    const unsigned done = atomicAdd(counter, 1u);
    if (done == (unsigned)(gridDim.x - 1)) {      // last block finalizes
      const float v = atomicAdd(lacc, 0.0f);      // device-scope read
      out[0] = v * (1.0f / (float)NROW);
    }
  }
}

extern "C" void kernel_launch(void* const* d_in, const int* in_sizes, int n_in,
                              void* d_out, int out_size, void* d_ws, size_t ws_size,
                              hipStream_t stream) {
  const float* z_i = (const float*)d_in[0];
  const float* z_j = (const float*)d_in[1];
  float* out = (float*)d_out;

  char* ws = (char*)d_ws;
  unsigned char* zn = (unsigned char*)ws;                        // 2 MB fp8
  float* pos  = (float*)(ws + 2097152);                          // 32 KB
  float* P    = (float*)(ws + 2097152 + 32768);                  // 2 MB
  float* lacc = (float*)(ws + 2097152 + 32768 + 2097152);        // 4 B
  unsigned int* counter = (unsigned int*)(ws + 2097152 + 32768 + 2097152 + 4);

  normalize_kernel<<<512, 256, 0, stream>>>(z_i, z_j, zn, lacc, counter);
  gram_kernel<<<NPAIRS, 512, 0, stream>>>(zn, P, pos);
  rowreduce_kernel<<<NROW / 256, 256, 0, stream>>>(P, pos, lacc, counter, out);
}